// Round 1
// baseline (381.679 us; speedup 1.0000x reference)
//
#include <hip/hip_runtime.h>
#include <hip/hip_bf16.h>

#define VIS_DIM 2048
#define TXT_DIM 1024
#define HID     1024
#define NB      128          // batch
#define NR      256          // regions
#define M_TOT   (NB*NR)      // 32768

typedef __attribute__((ext_vector_type(4))) float  f32x4;
typedef __attribute__((ext_vector_type(8))) short  short8;   // 8 x bf16 (4 VGPR)
typedef __attribute__((ext_vector_type(4))) unsigned short u16x4;

static __device__ __forceinline__ unsigned short f2bf(float f) {
    union { __hip_bfloat16 h; unsigned short u; } c;
    c.h = __float2bfloat16(f);
    return c.u;
}

static __device__ __forceinline__ float tanh_fast(float x) {
    float xc = fminf(fmaxf(x, -15.f), 15.f);
    float e  = __expf(2.f * xc);
    return (e - 1.f) / (e + 1.f);
}

// ---------------------------------------------------------------------------
// init: zero scores, t = bt broadcast (atomics accumulate on top)
// ---------------------------------------------------------------------------
__global__ void init_ws(float* __restrict__ scores, float* __restrict__ tbuf,
                        const float* __restrict__ bt) {
    int i = blockIdx.x * 256 + threadIdx.x;        // grid covers 131072
    if (i < M_TOT) scores[i] = 0.f;
    tbuf[i] = bt[i & (HID - 1)];
}

// ---------------------------------------------------------------------------
// t = text @ Wt^T (+bt already in tbuf). Split-K fp32 tiled GEMM, atomicAdd.
// grid (32 n-tiles of 32, 4 k-chunks of 256), block 256
// ---------------------------------------------------------------------------
__global__ __launch_bounds__(256) void gemm_text(const float* __restrict__ text,
                                                 const float* __restrict__ Wt,
                                                 float* __restrict__ tbuf) {
    __shared__ float As[128][33];
    __shared__ float Bs[32][33];
    const int n0  = blockIdx.x * 32;
    const int k0  = blockIdx.y * 256;
    const int tid = threadIdx.x;
    const int tm  = tid >> 3;   // 0..31 -> rows tm*4..+3
    const int tn  = tid & 7;    // 0..7  -> cols tn*4..+3
    float acc[4][4] = {};
    for (int kt = 0; kt < 8; ++kt) {
        const int k = k0 + kt * 32;
        {   // stage A: 128x32
            int row = tid >> 1, off = (tid & 1) * 16;
            const float* src = text + row * TXT_DIM + k + off;
            #pragma unroll
            for (int j = 0; j < 4; ++j) {
                f32x4 v = *(const f32x4*)(src + j * 4);
                As[row][off + j*4 + 0] = v.x; As[row][off + j*4 + 1] = v.y;
                As[row][off + j*4 + 2] = v.z; As[row][off + j*4 + 3] = v.w;
            }
        }
        {   // stage B: 32x32
            int row = tid >> 3, off = (tid & 7) * 4;
            f32x4 v = *(const f32x4*)(Wt + (size_t)(n0 + row) * TXT_DIM + k + off);
            Bs[row][off + 0] = v.x; Bs[row][off + 1] = v.y;
            Bs[row][off + 2] = v.z; Bs[row][off + 3] = v.w;
        }
        __syncthreads();
        #pragma unroll
        for (int kk = 0; kk < 32; ++kk) {
            float a[4], b[4];
            #pragma unroll
            for (int i = 0; i < 4; ++i) a[i] = As[tm*4 + i][kk];
            #pragma unroll
            for (int j = 0; j < 4; ++j) b[j] = Bs[tn*4 + j][kk];
            #pragma unroll
            for (int i = 0; i < 4; ++i)
                #pragma unroll
                for (int j = 0; j < 4; ++j) acc[i][j] += a[i] * b[j];
        }
        __syncthreads();
    }
    #pragma unroll
    for (int i = 0; i < 4; ++i)
        #pragma unroll
        for (int j = 0; j < 4; ++j)
            atomicAdd(&tbuf[(tm*4 + i) * HID + n0 + tn*4 + j], acc[i][j]);
}

// ---------------------------------------------------------------------------
// Main fused GEMM: scores[row] += sum_col Wa[col]*tanh(A@Wv^T + bv + t)
// bf16 MFMA 16x16x32, BM=BN=128, BK=64, 4 waves, reg-staged fp32->bf16,
// XOR-swizzled LDS, 2-phase double buffer (1 barrier/iter).
// ---------------------------------------------------------------------------
#define BK 64
#define NT (VIS_DIM / BK)    // 32

static __device__ __forceinline__ int lds_off(int which, int buf, int row, int k) {
    // bf16 tile [128][64], 16B slot-swizzled: slot ^= row&7
    int slot = k >> 3;
    int sub  = k & 7;
    return buf * 32768 + which * 16384 + row * 128 + ((slot ^ (row & 7)) << 4) + sub * 2;
}

__global__ __launch_bounds__(256, 2) void gemm_vis(
        const float* __restrict__ A,     // visual  32768 x 2048
        const float* __restrict__ Bv,    // Wv      1024 x 2048
        const float* __restrict__ bv,
        const float* __restrict__ wa,    // Wa[0]   1024
        const float* __restrict__ tbuf,  // 128 x 1024
        float* __restrict__ scores) {
    __shared__ __align__(16) char lds[65536];

    // XCD-aware bijective swizzle (2048 % 8 == 0)
    int wg  = blockIdx.x;
    int swz = (wg & 7) * 256 + (wg >> 3);
    const int nb   = swz & 7;
    const int mb   = swz >> 3;
    const int bcol = nb * 128;
    const int brow = mb * 128;

    const int tid  = threadIdx.x;
    const int lane = tid & 63;
    const int wid  = tid >> 6;
    const int wr   = wid >> 1, wc = wid & 1;   // 2x2 waves of 64x64

    const int srow = tid >> 4;   // 0..15
    const int sf4  = tid & 15;   // float4 index within a 64-elem row

    f32x4 ra[8], rb[8];
    f32x4 acc[4][4] = {};

    auto gload = [&](int kt) {
        const float* pa = A  + (size_t)brow * VIS_DIM + kt * BK + sf4 * 4;
        const float* pb = Bv + (size_t)bcol * VIS_DIM + kt * BK + sf4 * 4;
        #pragma unroll
        for (int i = 0; i < 8; ++i) {
            int row = i * 16 + srow;
            ra[i] = *(const f32x4*)(pa + (size_t)row * VIS_DIM);
            rb[i] = *(const f32x4*)(pb + (size_t)row * VIS_DIM);
        }
    };
    auto lwrite = [&](int buf) {
        #pragma unroll
        for (int i = 0; i < 8; ++i) {
            int row = i * 16 + srow;
            int k   = sf4 * 4;
            u16x4 va, vb;
            va.x = f2bf(ra[i].x); va.y = f2bf(ra[i].y); va.z = f2bf(ra[i].z); va.w = f2bf(ra[i].w);
            vb.x = f2bf(rb[i].x); vb.y = f2bf(rb[i].y); vb.z = f2bf(rb[i].z); vb.w = f2bf(rb[i].w);
            *(u16x4*)(lds + lds_off(0, buf, row, k)) = va;
            *(u16x4*)(lds + lds_off(1, buf, row, k)) = vb;
        }
    };
    auto compute = [&](int buf) {
        #pragma unroll
        for (int ks = 0; ks < 2; ++ks) {
            short8 af[4], bf[4];
            const int kk = ks * 32 + (lane >> 4) * 8;
            #pragma unroll
            for (int m = 0; m < 4; ++m) {
                int row = wr * 64 + m * 16 + (lane & 15);
                af[m] = *(const short8*)(lds + lds_off(0, buf, row, kk));
            }
            #pragma unroll
            for (int n = 0; n < 4; ++n) {
                int col = wc * 64 + n * 16 + (lane & 15);
                bf[n] = *(const short8*)(lds + lds_off(1, buf, col, kk));
            }
            #pragma unroll
            for (int m = 0; m < 4; ++m)
                #pragma unroll
                for (int n = 0; n < 4; ++n)
                    acc[m][n] = __builtin_amdgcn_mfma_f32_16x16x32_bf16(
                        af[m], bf[n], acc[m][n], 0, 0, 0);
        }
    };

    gload(0);
    lwrite(0);
    for (int kt = 0; kt < NT; ++kt) {
        __syncthreads();
        if (kt + 1 < NT) gload(kt + 1);
        compute(kt & 1);
        if (kt + 1 < NT) lwrite((kt + 1) & 1);
    }

    // ---- epilogue: tanh + Wa-dot, reduce over 16 cols/lane-group, atomicAdd
    const int b = brow >> 8;                 // batch index (tile fits in one b)
    float wa_c[4], bvt_c[4];
    #pragma unroll
    for (int n = 0; n < 4; ++n) {
        int col = bcol + wc * 64 + n * 16 + (lane & 15);
        wa_c[n]  = wa[col];
        bvt_c[n] = bv[col] + tbuf[b * HID + col];
    }
    #pragma unroll
    for (int m = 0; m < 4; ++m) {
        float p0 = 0.f, p1 = 0.f, p2 = 0.f, p3 = 0.f;
        #pragma unroll
        for (int n = 0; n < 4; ++n) {
            f32x4 v = acc[m][n];
            p0 += wa_c[n] * tanh_fast(v.x + bvt_c[n]);
            p1 += wa_c[n] * tanh_fast(v.y + bvt_c[n]);
            p2 += wa_c[n] * tanh_fast(v.z + bvt_c[n]);
            p3 += wa_c[n] * tanh_fast(v.w + bvt_c[n]);
        }
        #pragma unroll
        for (int d = 1; d < 16; d <<= 1) {
            p0 += __shfl_xor(p0, d); p1 += __shfl_xor(p1, d);
            p2 += __shfl_xor(p2, d); p3 += __shfl_xor(p3, d);
        }
        if ((lane & 15) == 0) {
            int rowg = brow + wr * 64 + m * 16 + (lane >> 4) * 4;
            atomicAdd(&scores[rowg + 0], p0);
            atomicAdd(&scores[rowg + 1], p1);
            atomicAdd(&scores[rowg + 2], p2);
            atomicAdd(&scores[rowg + 3], p3);
        }
    }
}

// ---------------------------------------------------------------------------
// softmax over regions + attended = w . visual ; grid (8 d-chunks, 128 b),
// block 256 (4 waves split the 256-region loop, LDS combine).
// ---------------------------------------------------------------------------
__global__ __launch_bounds__(256) void attend(const float* __restrict__ visual,
                                              const float* __restrict__ scores,
                                              float* __restrict__ out) {
    const int chunk = blockIdx.x;   // 0..7 -> 256 d each
    const int b     = blockIdx.y;   // 0..127
    const int tid   = threadIdx.x;
    const int lane  = tid & 63;
    const int wv    = tid >> 6;

    __shared__ float wsm[NR];
    __shared__ float red[4];
    __shared__ f32x4 part[4][64];

    float s = scores[b * NR + tid];
    float mx = s;
    #pragma unroll
    for (int d = 1; d < 64; d <<= 1) mx = fmaxf(mx, __shfl_xor(mx, d));
    if (lane == 0) red[wv] = mx;
    __syncthreads();
    mx = fmaxf(fmaxf(red[0], red[1]), fmaxf(red[2], red[3]));
    float e = __expf(s - mx);
    float sum = e;
    #pragma unroll
    for (int d = 1; d < 64; d <<= 1) sum += __shfl_xor(sum, d);
    __syncthreads();
    if (lane == 0) red[wv] = sum;
    __syncthreads();
    sum = red[0] + red[1] + red[2] + red[3];
    float w = e * (1.f / sum);
    wsm[tid] = w;
    if (chunk == 0) out[(size_t)NB * VIS_DIM + b * NR + tid] = w;
    __syncthreads();

    const float* vb = visual + ((size_t)b * NR + wv * 64) * VIS_DIM + chunk * 256 + lane * 4;
    f32x4 acc = {0.f, 0.f, 0.f, 0.f};
    #pragma unroll
    for (int r = 0; r < 64; r += 4) {
        f32x4 v0 = *(const f32x4*)(vb + (size_t)(r + 0) * VIS_DIM);
        f32x4 v1 = *(const f32x4*)(vb + (size_t)(r + 1) * VIS_DIM);
        f32x4 v2 = *(const f32x4*)(vb + (size_t)(r + 2) * VIS_DIM);
        f32x4 v3 = *(const f32x4*)(vb + (size_t)(r + 3) * VIS_DIM);
        acc += wsm[wv * 64 + r + 0] * v0;
        acc += wsm[wv * 64 + r + 1] * v1;
        acc += wsm[wv * 64 + r + 2] * v2;
        acc += wsm[wv * 64 + r + 3] * v3;
    }
    part[wv][lane] = acc;
    __syncthreads();
    if (wv == 0) {
        f32x4 a = part[0][lane] + part[1][lane] + part[2][lane] + part[3][lane];
        *(f32x4*)(out + (size_t)b * VIS_DIM + chunk * 256 + lane * 4) = a;
    }
}

// ---------------------------------------------------------------------------
extern "C" void kernel_launch(void* const* d_in, const int* in_sizes, int n_in,
                              void* d_out, int out_size, void* d_ws, size_t ws_size,
                              hipStream_t stream) {
    (void)in_sizes; (void)n_in; (void)out_size; (void)ws_size;
    const float* visual = (const float*)d_in[0];
    const float* text   = (const float*)d_in[1];
    const float* Wv     = (const float*)d_in[2];
    const float* bv     = (const float*)d_in[3];
    const float* Wt     = (const float*)d_in[4];
    const float* bt     = (const float*)d_in[5];
    const float* Wa     = (const float*)d_in[6];
    // d_in[7] = ba : softmax-shift-invariant, unused.

    float* out    = (float*)d_out;
    float* scores = (float*)d_ws;          // 32768 f32
    float* tbuf   = scores + M_TOT;        // 131072 f32  (total ws use: 640 KiB)

    init_ws  <<<512, 256, 0, stream>>>(scores, tbuf, bt);
    gemm_text<<<dim3(32, 4), 256, 0, stream>>>(text, Wt, tbuf);
    gemm_vis <<<2048, 256, 0, stream>>>(visual, Wv, bv, Wa, tbuf, scores);
    attend   <<<dim3(8, NB), 256, 0, stream>>>(visual, scores, out);
}

// Round 2
// 299.930 us; speedup vs baseline: 1.2726x; 1.2726x over previous
//
#include <hip/hip_runtime.h>
#include <hip/hip_bf16.h>

#define VIS_DIM 2048
#define TXT_DIM 1024
#define HID     1024
#define NB      128          // batch
#define NR      256          // regions
#define M_TOT   (NB*NR)      // 32768

typedef __attribute__((ext_vector_type(4))) float  f32x4;
typedef __attribute__((ext_vector_type(8))) short  short8;   // 8 x bf16 (4 VGPR)
typedef __attribute__((ext_vector_type(4))) unsigned short u16x4;

static __device__ __forceinline__ unsigned short f2bf(float f) {
    union { __hip_bfloat16 h; unsigned short u; } c;
    c.h = __float2bfloat16(f);
    return c.u;
}

static __device__ __forceinline__ float tanh_fast(float x) {
    float xc = fminf(fmaxf(x, -15.f), 15.f);
    float e  = __expf(2.f * xc);
    return (e - 1.f) / (e + 1.f);
}

// ---------------------------------------------------------------------------
// init: zero scores, t = bt broadcast (atomics accumulate on top)
// ---------------------------------------------------------------------------
__global__ void init_ws(float* __restrict__ scores, float* __restrict__ tbuf,
                        const float* __restrict__ bt) {
    int i = blockIdx.x * 256 + threadIdx.x;        // grid covers 131072
    if (i < M_TOT) scores[i] = 0.f;
    tbuf[i] = bt[i & (HID - 1)];
}

// ---------------------------------------------------------------------------
// t = text @ Wt^T (+bt already in tbuf). Split-K fp32 tiled GEMM, atomicAdd.
// grid (32 n-tiles of 32, 4 k-chunks of 256), block 256
// ---------------------------------------------------------------------------
__global__ __launch_bounds__(256) void gemm_text(const float* __restrict__ text,
                                                 const float* __restrict__ Wt,
                                                 float* __restrict__ tbuf) {
    __shared__ float As[128][33];
    __shared__ float Bs[32][33];
    const int n0  = blockIdx.x * 32;
    const int k0  = blockIdx.y * 256;
    const int tid = threadIdx.x;
    const int tm  = tid >> 3;   // 0..31 -> rows tm*4..+3
    const int tn  = tid & 7;    // 0..7  -> cols tn*4..+3
    float acc[4][4] = {};
    for (int kt = 0; kt < 8; ++kt) {
        const int k = k0 + kt * 32;
        {   // stage A: 128x32
            int row = tid >> 1, off = (tid & 1) * 16;
            const float* src = text + row * TXT_DIM + k + off;
            #pragma unroll
            for (int j = 0; j < 4; ++j) {
                f32x4 v = *(const f32x4*)(src + j * 4);
                As[row][off + j*4 + 0] = v.x; As[row][off + j*4 + 1] = v.y;
                As[row][off + j*4 + 2] = v.z; As[row][off + j*4 + 3] = v.w;
            }
        }
        {   // stage B: 32x32
            int row = tid >> 3, off = (tid & 7) * 4;
            f32x4 v = *(const f32x4*)(Wt + (size_t)(n0 + row) * TXT_DIM + k + off);
            Bs[row][off + 0] = v.x; Bs[row][off + 1] = v.y;
            Bs[row][off + 2] = v.z; Bs[row][off + 3] = v.w;
        }
        __syncthreads();
        #pragma unroll
        for (int kk = 0; kk < 32; ++kk) {
            float a[4], b[4];
            #pragma unroll
            for (int i = 0; i < 4; ++i) a[i] = As[tm*4 + i][kk];
            #pragma unroll
            for (int j = 0; j < 4; ++j) b[j] = Bs[tn*4 + j][kk];
            #pragma unroll
            for (int i = 0; i < 4; ++i)
                #pragma unroll
                for (int j = 0; j < 4; ++j) acc[i][j] += a[i] * b[j];
        }
        __syncthreads();
    }
    #pragma unroll
    for (int i = 0; i < 4; ++i)
        #pragma unroll
        for (int j = 0; j < 4; ++j)
            atomicAdd(&tbuf[(tm*4 + i) * HID + n0 + tn*4 + j], acc[i][j]);
}

// ---------------------------------------------------------------------------
// Main fused GEMM: scores[row] += sum_col Wa[col]*tanh(A@Wv^T + bv + t)
// bf16 MFMA 16x16x32, BM=BN=128, BK=64, 4 waves, reg-staged fp32->bf16,
// XOR-swizzled LDS, 2-phase double buffer (1 barrier/iter).
//
// R1 fix: VGPR=88 showed the compiler sank the prefetch loads into lwrite
// (8x serialized latency/iter -> 8100 cyc/iter, MfmaUtil 13%). Pin the
// schedule with sched_barrier(0): loads issue BEFORE the MFMA block, the
// vmcnt drain lands AFTER it. Expect VGPR ~200 (prefetch actually live).
// ---------------------------------------------------------------------------
#define BK 64
#define NT (VIS_DIM / BK)    // 32

static __device__ __forceinline__ int lds_off(int which, int buf, int row, int k) {
    // bf16 tile [128][64], 16B slot-swizzled: slot ^= row&7
    int slot = k >> 3;
    int sub  = k & 7;
    return buf * 32768 + which * 16384 + row * 128 + ((slot ^ (row & 7)) << 4) + sub * 2;
}

__global__ __launch_bounds__(256, 2) void gemm_vis(
        const float* __restrict__ A,     // visual  32768 x 2048
        const float* __restrict__ Bv,    // Wv      1024 x 2048
        const float* __restrict__ bv,
        const float* __restrict__ wa,    // Wa[0]   1024
        const float* __restrict__ tbuf,  // 128 x 1024
        float* __restrict__ scores) {
    __shared__ __align__(16) char lds[65536];

    // XCD-aware bijective swizzle (2048 % 8 == 0)
    int wg  = blockIdx.x;
    int swz = (wg & 7) * 256 + (wg >> 3);
    const int nb   = swz & 7;
    const int mb   = swz >> 3;
    const int bcol = nb * 128;
    const int brow = mb * 128;

    const int tid  = threadIdx.x;
    const int lane = tid & 63;
    const int wid  = tid >> 6;
    const int wr   = wid >> 1, wc = wid & 1;   // 2x2 waves of 64x64

    const int srow = tid >> 4;   // 0..15
    const int sf4  = tid & 15;   // float4 index within a 64-elem row

    f32x4 ra[8], rb[8];
    f32x4 acc[4][4] = {};

    auto gload = [&](int kt) {
        const float* pa = A  + (size_t)brow * VIS_DIM + kt * BK + sf4 * 4;
        const float* pb = Bv + (size_t)bcol * VIS_DIM + kt * BK + sf4 * 4;
        #pragma unroll
        for (int i = 0; i < 8; ++i) {
            int row = i * 16 + srow;
            ra[i] = *(const f32x4*)(pa + (size_t)row * VIS_DIM);
            rb[i] = *(const f32x4*)(pb + (size_t)row * VIS_DIM);
        }
    };
    auto lwrite = [&](int buf) {
        #pragma unroll
        for (int i = 0; i < 8; ++i) {
            int row = i * 16 + srow;
            int k   = sf4 * 4;
            u16x4 va, vb;
            va.x = f2bf(ra[i].x); va.y = f2bf(ra[i].y); va.z = f2bf(ra[i].z); va.w = f2bf(ra[i].w);
            vb.x = f2bf(rb[i].x); vb.y = f2bf(rb[i].y); vb.z = f2bf(rb[i].z); vb.w = f2bf(rb[i].w);
            *(u16x4*)(lds + lds_off(0, buf, row, k)) = va;
            *(u16x4*)(lds + lds_off(1, buf, row, k)) = vb;
        }
    };
    auto compute = [&](int buf) {
        #pragma unroll
        for (int ks = 0; ks < 2; ++ks) {
            short8 af[4], bf[4];
            const int kk = ks * 32 + (lane >> 4) * 8;
            #pragma unroll
            for (int m = 0; m < 4; ++m) {
                int row = wr * 64 + m * 16 + (lane & 15);
                af[m] = *(const short8*)(lds + lds_off(0, buf, row, kk));
            }
            #pragma unroll
            for (int n = 0; n < 4; ++n) {
                int col = wc * 64 + n * 16 + (lane & 15);
                bf[n] = *(const short8*)(lds + lds_off(1, buf, col, kk));
            }
            #pragma unroll
            for (int m = 0; m < 4; ++m)
                #pragma unroll
                for (int n = 0; n < 4; ++n)
                    acc[m][n] = __builtin_amdgcn_mfma_f32_16x16x32_bf16(
                        af[m], bf[n], acc[m][n], 0, 0, 0);
        }
    };

    gload(0);
    lwrite(0);
    for (int kt = 0; kt < NT; ++kt) {
        __syncthreads();
        if (kt + 1 < NT) {
            gload(kt + 1);
            // Pin: all 32 dwordx4 issue HERE, before the MFMA block. Without
            // this the scheduler sinks them into lwrite (R1: VGPR=88, 8x
            // serialized latency per iter).
            __builtin_amdgcn_sched_barrier(0);
        }
        compute(kt & 1);
        if (kt + 1 < NT) {
            // Pin: MFMAs stay above; the vmcnt drain for the prefetch and the
            // ds_writes happen after compute, overlapped with its latency.
            __builtin_amdgcn_sched_barrier(0);
            lwrite((kt + 1) & 1);
        }
    }

    // ---- epilogue: tanh + Wa-dot, reduce over 16 cols/lane-group, atomicAdd
    const int b = brow >> 8;                 // batch index (tile fits in one b)
    float wa_c[4], bvt_c[4];
    #pragma unroll
    for (int n = 0; n < 4; ++n) {
        int col = bcol + wc * 64 + n * 16 + (lane & 15);
        wa_c[n]  = wa[col];
        bvt_c[n] = bv[col] + tbuf[b * HID + col];
    }
    #pragma unroll
    for (int m = 0; m < 4; ++m) {
        float p0 = 0.f, p1 = 0.f, p2 = 0.f, p3 = 0.f;
        #pragma unroll
        for (int n = 0; n < 4; ++n) {
            f32x4 v = acc[m][n];
            p0 += wa_c[n] * tanh_fast(v.x + bvt_c[n]);
            p1 += wa_c[n] * tanh_fast(v.y + bvt_c[n]);
            p2 += wa_c[n] * tanh_fast(v.z + bvt_c[n]);
            p3 += wa_c[n] * tanh_fast(v.w + bvt_c[n]);
        }
        #pragma unroll
        for (int d = 1; d < 16; d <<= 1) {
            p0 += __shfl_xor(p0, d); p1 += __shfl_xor(p1, d);
            p2 += __shfl_xor(p2, d); p3 += __shfl_xor(p3, d);
        }
        if ((lane & 15) == 0) {
            int rowg = brow + wr * 64 + m * 16 + (lane >> 4) * 4;
            atomicAdd(&scores[rowg + 0], p0);
            atomicAdd(&scores[rowg + 1], p1);
            atomicAdd(&scores[rowg + 2], p2);
            atomicAdd(&scores[rowg + 3], p3);
        }
    }
}

// ---------------------------------------------------------------------------
// softmax over regions + attended = w . visual ; grid (8 d-chunks, 128 b),
// block 256 (4 waves split the 256-region loop, LDS combine).
// ---------------------------------------------------------------------------
__global__ __launch_bounds__(256) void attend(const float* __restrict__ visual,
                                              const float* __restrict__ scores,
                                              float* __restrict__ out) {
    const int chunk = blockIdx.x;   // 0..7 -> 256 d each
    const int b     = blockIdx.y;   // 0..127
    const int tid   = threadIdx.x;
    const int lane  = tid & 63;
    const int wv    = tid >> 6;

    __shared__ float wsm[NR];
    __shared__ float red[4];
    __shared__ f32x4 part[4][64];

    float s = scores[b * NR + tid];
    float mx = s;
    #pragma unroll
    for (int d = 1; d < 64; d <<= 1) mx = fmaxf(mx, __shfl_xor(mx, d));
    if (lane == 0) red[wv] = mx;
    __syncthreads();
    mx = fmaxf(fmaxf(red[0], red[1]), fmaxf(red[2], red[3]));
    float e = __expf(s - mx);
    float sum = e;
    #pragma unroll
    for (int d = 1; d < 64; d <<= 1) sum += __shfl_xor(sum, d);
    __syncthreads();
    if (lane == 0) red[wv] = sum;
    __syncthreads();
    sum = red[0] + red[1] + red[2] + red[3];
    float w = e * (1.f / sum);
    wsm[tid] = w;
    if (chunk == 0) out[(size_t)NB * VIS_DIM + b * NR + tid] = w;
    __syncthreads();

    const float* vb = visual + ((size_t)b * NR + wv * 64) * VIS_DIM + chunk * 256 + lane * 4;
    f32x4 acc = {0.f, 0.f, 0.f, 0.f};
    #pragma unroll
    for (int r = 0; r < 64; r += 4) {
        f32x4 v0 = *(const f32x4*)(vb + (size_t)(r + 0) * VIS_DIM);
        f32x4 v1 = *(const f32x4*)(vb + (size_t)(r + 1) * VIS_DIM);
        f32x4 v2 = *(const f32x4*)(vb + (size_t)(r + 2) * VIS_DIM);
        f32x4 v3 = *(const f32x4*)(vb + (size_t)(r + 3) * VIS_DIM);
        acc += wsm[wv * 64 + r + 0] * v0;
        acc += wsm[wv * 64 + r + 1] * v1;
        acc += wsm[wv * 64 + r + 2] * v2;
        acc += wsm[wv * 64 + r + 3] * v3;
    }
    part[wv][lane] = acc;
    __syncthreads();
    if (wv == 0) {
        f32x4 a = part[0][lane] + part[1][lane] + part[2][lane] + part[3][lane];
        *(f32x4*)(out + (size_t)b * VIS_DIM + chunk * 256 + lane * 4) = a;
    }
}

// ---------------------------------------------------------------------------
extern "C" void kernel_launch(void* const* d_in, const int* in_sizes, int n_in,
                              void* d_out, int out_size, void* d_ws, size_t ws_size,
                              hipStream_t stream) {
    (void)in_sizes; (void)n_in; (void)out_size; (void)ws_size;
    const float* visual = (const float*)d_in[0];
    const float* text   = (const float*)d_in[1];
    const float* Wv     = (const float*)d_in[2];
    const float* bv     = (const float*)d_in[3];
    const float* Wt     = (const float*)d_in[4];
    const float* bt     = (const float*)d_in[5];
    const float* Wa     = (const float*)d_in[6];
    // d_in[7] = ba : softmax-shift-invariant, unused.

    float* out    = (float*)d_out;
    float* scores = (float*)d_ws;          // 32768 f32
    float* tbuf   = scores + M_TOT;        // 131072 f32  (total ws use: 640 KiB)

    init_ws  <<<512, 256, 0, stream>>>(scores, tbuf, bt);
    gemm_text<<<dim3(32, 4), 256, 0, stream>>>(text, Wt, tbuf);
    gemm_vis <<<2048, 256, 0, stream>>>(visual, Wv, bv, Wa, tbuf, scores);
    attend   <<<dim3(8, NB), 256, 0, stream>>>(visual, scores, out);
}